// Round 1
// baseline (13704.245 us; speedup 1.0000x reference)
//
#include <hip/hip_runtime.h>
#include <math.h>

#define N_ 128
#define T_ 512
#define D_ 1024
#define H_ 1024

// ---------------------------------------------------------------------------
// Phase 1: xw = x @ Wx + b, written straight into d_out (same (N,T,H) layout).
// M = N_*T_ = 65536 rows. 128x128 tile, 256 threads, 8x8 micro-tile, K-step 8.
// fp32 vector FMA (no fp32 MFMA on CDNA4).
// ---------------------------------------------------------------------------
__global__ __launch_bounds__(256) void gemm_xw(
    const float* __restrict__ A,    // (M, D_) row-major
    const float* __restrict__ B,    // (D_, H_) row-major
    const float* __restrict__ bias, // (H_)
    float* __restrict__ C)          // (M, H_) row-major
{
    __shared__ float As[8][128];   // transposed A tile: As[k][m]
    __shared__ float Bs[8][128];   // Bs[k][n]

    const int tid = threadIdx.x;
    const int m0 = blockIdx.x * 128;
    const int n0 = blockIdx.y * 128;

    // loader indices
    const int la_m = tid & 127;          // row within tile
    const int la_k = (tid >> 7) * 4;     // k group of 4
    const int lb_k = tid >> 5;           // 0..7
    const int lb_n = (tid & 31) * 4;

    // compute indices: 16x16 threads, each 8x8 outputs
    const int tx = tid & 15;
    const int ty = tid >> 4;
    const int cm = ty * 8;
    const int cn = tx * 8;

    float acc[8][8];
#pragma unroll
    for (int i = 0; i < 8; i++)
#pragma unroll
        for (int j = 0; j < 8; j++) acc[i][j] = 0.f;

    const float* aptr = A + (long)(m0 + la_m) * D_ + la_k;
    const float* bptr = B + (long)lb_k * H_ + n0 + lb_n;

    for (int k0 = 0; k0 < D_; k0 += 8) {
        float4 av = *(const float4*)(aptr + k0);
        float4 bv = *(const float4*)(bptr + (long)k0 * H_);
        As[la_k + 0][la_m] = av.x;
        As[la_k + 1][la_m] = av.y;
        As[la_k + 2][la_m] = av.z;
        As[la_k + 3][la_m] = av.w;
        *(float4*)&Bs[lb_k][lb_n] = bv;
        __syncthreads();
#pragma unroll
        for (int k = 0; k < 8; k++) {
            float a0[8], b0[8];
            *(float4*)&a0[0] = *(const float4*)&As[k][cm];
            *(float4*)&a0[4] = *(const float4*)&As[k][cm + 4];
            *(float4*)&b0[0] = *(const float4*)&Bs[k][cn];
            *(float4*)&b0[4] = *(const float4*)&Bs[k][cn + 4];
#pragma unroll
            for (int i = 0; i < 8; i++)
#pragma unroll
                for (int j = 0; j < 8; j++)
                    acc[i][j] = fmaf(a0[i], b0[j], acc[i][j]);
        }
        __syncthreads();
    }

#pragma unroll
    for (int i = 0; i < 8; i++) {
        long row = (long)(m0 + cm + i) * H_ + n0;
#pragma unroll
        for (int j = 0; j < 8; j += 4) {
            float4 v;
            v.x = acc[i][j + 0] + bias[n0 + cn + j + 0];
            v.y = acc[i][j + 1] + bias[n0 + cn + j + 1];
            v.z = acc[i][j + 2] + bias[n0 + cn + j + 2];
            v.w = acc[i][j + 3] + bias[n0 + cn + j + 3];
            *(float4*)&C[row + cn + j] = v;
        }
    }
}

// ---------------------------------------------------------------------------
// Phase 2: one timestep.  out_t[n][j] = tanh(out_t[n][j] + sum_k h[n][k]*Wh[k][j])
// h_prev is read from h0 (stride H_) at t=0, else from d_out slice t-1
// (stride T_*H_).  In-place on the d_out slice for step t.
// grid = 512 blocks: (n = bid>>2, 256-col chunk = bid&3), 256 threads,
// 1 output column per thread; h row staged in LDS (broadcast reads).
// ---------------------------------------------------------------------------
__global__ __launch_bounds__(256) void rnn_step(
    const float* __restrict__ hprev, long hstride,
    const float* __restrict__ Wh,   // (H_, H_) row-major
    float* __restrict__ out_t)      // d_out + t*H_; element (n,j) at n*T_*H_ + j
{
    __shared__ float hs[H_];
    const int n = blockIdx.x >> 2;
    const int j = ((blockIdx.x & 3) << 8) + threadIdx.x;

    // stage h row (1024 floats, 256 threads x float4)
    *(float4*)&hs[threadIdx.x * 4] =
        *(const float4*)&hprev[(long)n * hstride + threadIdx.x * 4];
    __syncthreads();

    const float* wcol = Wh + j;
    float acc0 = 0.f, acc1 = 0.f, acc2 = 0.f, acc3 = 0.f;
#pragma unroll 4
    for (int k = 0; k < H_; k += 4) {
        acc0 = fmaf(hs[k + 0], wcol[(long)(k + 0) * H_], acc0);
        acc1 = fmaf(hs[k + 1], wcol[(long)(k + 1) * H_], acc1);
        acc2 = fmaf(hs[k + 2], wcol[(long)(k + 2) * H_], acc2);
        acc3 = fmaf(hs[k + 3], wcol[(long)(k + 3) * H_], acc3);
    }
    long oidx = (long)n * (T_ * H_) + j;
    out_t[oidx] = tanhf(out_t[oidx] + (acc0 + acc1) + (acc2 + acc3));
}

// ---------------------------------------------------------------------------
extern "C" void kernel_launch(void* const* d_in, const int* in_sizes, int n_in,
                              void* d_out, int out_size, void* d_ws, size_t ws_size,
                              hipStream_t stream) {
    const float* x  = (const float*)d_in[0]; // (N, T, D)
    const float* h0 = (const float*)d_in[1]; // (N, H)
    const float* Wx = (const float*)d_in[2]; // (D, H)
    const float* Wh = (const float*)d_in[3]; // (H, H)
    const float* b  = (const float*)d_in[4]; // (H)
    float* out = (float*)d_out;              // (N, T, H)

    // Phase 1: xw -> d_out
    dim3 g1((N_ * T_) / 128, H_ / 128); // 512 x 8
    gemm_xw<<<g1, 256, 0, stream>>>(x, Wx, b, out);

    // Phase 2: sequential scan, in-place on d_out slices
    for (int t = 0; t < T_; t++) {
        const float* hp = (t == 0) ? h0 : (out + (long)(t - 1) * H_);
        long hstride = (t == 0) ? (long)H_ : (long)T_ * H_;
        rnn_step<<<dim3(N_ * 4), 256, 0, stream>>>(hp, hstride, Wh,
                                                   out + (long)t * H_);
    }
}

// Round 2
// 11522.379 us; speedup vs baseline: 1.1894x; 1.1894x over previous
//
#include <hip/hip_runtime.h>
#include <math.h>

#define N_ 128
#define T_ 512
#define D_ 1024
#define H_ 1024

// ---------------------------------------------------------------------------
// Phase 1: xw = x @ Wx + b -> d_out (same (N,T,H) layout). Unchanged from R0.
// ---------------------------------------------------------------------------
__global__ __launch_bounds__(256) void gemm_xw(
    const float* __restrict__ A,    // (M, D_) row-major
    const float* __restrict__ B,    // (D_, H_) row-major
    const float* __restrict__ bias, // (H_)
    float* __restrict__ C)          // (M, H_) row-major
{
    __shared__ float As[8][128];
    __shared__ float Bs[8][128];

    const int tid = threadIdx.x;
    const int m0 = blockIdx.x * 128;
    const int n0 = blockIdx.y * 128;

    const int la_m = tid & 127;
    const int la_k = (tid >> 7) * 4;
    const int lb_k = tid >> 5;
    const int lb_n = (tid & 31) * 4;

    const int tx = tid & 15;
    const int ty = tid >> 4;
    const int cm = ty * 8;
    const int cn = tx * 8;

    float acc[8][8];
#pragma unroll
    for (int i = 0; i < 8; i++)
#pragma unroll
        for (int j = 0; j < 8; j++) acc[i][j] = 0.f;

    const float* aptr = A + (long)(m0 + la_m) * D_ + la_k;
    const float* bptr = B + (long)lb_k * H_ + n0 + lb_n;

    for (int k0 = 0; k0 < D_; k0 += 8) {
        float4 av = *(const float4*)(aptr + k0);
        float4 bv = *(const float4*)(bptr + (long)k0 * H_);
        As[la_k + 0][la_m] = av.x;
        As[la_k + 1][la_m] = av.y;
        As[la_k + 2][la_m] = av.z;
        As[la_k + 3][la_m] = av.w;
        *(float4*)&Bs[lb_k][lb_n] = bv;
        __syncthreads();
#pragma unroll
        for (int k = 0; k < 8; k++) {
            float a0[8], b0[8];
            *(float4*)&a0[0] = *(const float4*)&As[k][cm];
            *(float4*)&a0[4] = *(const float4*)&As[k][cm + 4];
            *(float4*)&b0[0] = *(const float4*)&Bs[k][cn];
            *(float4*)&b0[4] = *(const float4*)&Bs[k][cn + 4];
#pragma unroll
            for (int i = 0; i < 8; i++)
#pragma unroll
                for (int j = 0; j < 8; j++)
                    acc[i][j] = fmaf(a0[i], b0[j], acc[i][j]);
        }
        __syncthreads();
    }

#pragma unroll
    for (int i = 0; i < 8; i++) {
        long row = (long)(m0 + cm + i) * H_ + n0;
#pragma unroll
        for (int j = 0; j < 8; j += 4) {
            float4 v;
            v.x = acc[i][j + 0] + bias[n0 + cn + j + 0];
            v.y = acc[i][j + 1] + bias[n0 + cn + j + 1];
            v.z = acc[i][j + 2] + bias[n0 + cn + j + 2];
            v.w = acc[i][j + 3] + bias[n0 + cn + j + 3];
            *(float4*)&C[row + cn + j] = v;
        }
    }
}

// ---------------------------------------------------------------------------
// Phase 2: one timestep, tiled so Wh is amortized across 16 batch rows.
// Grid 256 = 8 m-tiles (16 rows) x 32 n-tiles (32 cols). Block 256 threads:
//   ks = tid>>7 (2-way K-split, 512 k each)
//   r  = (tid>>3)&15 (row in tile)
//   cg = tid&7 (float4 col group: cols n0+cg*4..+3)
// h-tile (16 x 1024) staged in LDS, padded stride 1028 -> per-k wave reads
// hit 8 distinct banks (conflict-free) + broadcast across cg lanes.
// Wh read from global (L2-resident, 4 MB): per wave/k only 8 distinct
// float4s (128 B contiguous), r-lanes dedupe in the coalescer.
// Per-step Wh traffic: 256 blocks * 128 KB = 32 MB (was 512 MB).
// ---------------------------------------------------------------------------
__global__ __launch_bounds__(256) void rnn_step(
    const float* __restrict__ hprev, long hstride,
    const float* __restrict__ Wh,   // (H_, H_) row-major
    float* __restrict__ out_t)      // d_out + t*H_; element (n,j) at n*T_*H_ + j
{
    __shared__ float hs[16][1028];   // padded: bank = (4r + k) & 31, 2-way max
    __shared__ float red[16][33];    // ks=1 partials

    const int tid = threadIdx.x;
    const int m0 = (blockIdx.x >> 5) * 16;
    const int n0 = (blockIdx.x & 31) * 32;

    // --- stage h tile: 16 rows x 1024 cols, coalesced float4 loads ---
    {
        const int lr = tid >> 4;         // 0..15
        const int lc = (tid & 15) * 4;   // 0..60
        const float* src = hprev + (long)(m0 + lr) * hstride;
#pragma unroll
        for (int i = 0; i < 16; i++) {
            *(float4*)&hs[lr][lc + i * 64] = *(const float4*)&src[lc + i * 64];
        }
    }
    __syncthreads();

    const int ks = tid >> 7;         // 0 or 1
    const int r  = (tid >> 3) & 15;
    const int cg = tid & 7;

    const float* wp   = Wh + (long)(ks * 512) * H_ + n0 + cg * 4;
    const float* hrow = &hs[r][ks * 512];

    float4 acc = make_float4(0.f, 0.f, 0.f, 0.f);
#pragma unroll 8
    for (int k = 0; k < 512; k++) {
        float hv = hrow[k];
        float4 w = *(const float4*)(wp + (long)k * H_);
        acc.x = fmaf(hv, w.x, acc.x);
        acc.y = fmaf(hv, w.y, acc.y);
        acc.z = fmaf(hv, w.z, acc.z);
        acc.w = fmaf(hv, w.w, acc.w);
    }

    if (ks == 1) {
        red[r][cg * 4 + 0] = acc.x;
        red[r][cg * 4 + 1] = acc.y;
        red[r][cg * 4 + 2] = acc.z;
        red[r][cg * 4 + 3] = acc.w;
    }
    __syncthreads();
    if (ks == 0) {
        long o = (long)(m0 + r) * (T_ * H_) + n0 + cg * 4;
        float4 xw4 = *(const float4*)&out_t[o];
        float4 res;
        res.x = tanhf(xw4.x + acc.x + red[r][cg * 4 + 0]);
        res.y = tanhf(xw4.y + acc.y + red[r][cg * 4 + 1]);
        res.z = tanhf(xw4.z + acc.z + red[r][cg * 4 + 2]);
        res.w = tanhf(xw4.w + acc.w + red[r][cg * 4 + 3]);
        *(float4*)&out_t[o] = res;
    }
}

// ---------------------------------------------------------------------------
extern "C" void kernel_launch(void* const* d_in, const int* in_sizes, int n_in,
                              void* d_out, int out_size, void* d_ws, size_t ws_size,
                              hipStream_t stream) {
    const float* x  = (const float*)d_in[0]; // (N, T, D)
    const float* h0 = (const float*)d_in[1]; // (N, H)
    const float* Wx = (const float*)d_in[2]; // (D, H)
    const float* Wh = (const float*)d_in[3]; // (H, H)
    const float* b  = (const float*)d_in[4]; // (H)
    float* out = (float*)d_out;              // (N, T, H)

    // Phase 1: xw -> d_out
    dim3 g1((N_ * T_) / 128, H_ / 128); // 512 x 8
    gemm_xw<<<g1, 256, 0, stream>>>(x, Wx, b, out);

    // Phase 2: sequential scan, in-place on d_out slices
    for (int t = 0; t < T_; t++) {
        const float* hp = (t == 0) ? h0 : (out + (long)(t - 1) * H_);
        long hstride = (t == 0) ? (long)H_ : (long)T_ * H_;
        rnn_step<<<dim3(256), 256, 0, stream>>>(hp, hstride, Wh,
                                                out + (long)t * H_);
    }
}